// Round 1
// baseline (79.592 us; speedup 1.0000x reference)
//
#include <hip/hip_runtime.h>
#include <hip/hip_bf16.h>

#define DEV __device__ __forceinline__

// ---- bf16 helpers (manual, RNE) ----
DEV float bf2f(unsigned short u) { return __uint_as_float(((unsigned)u) << 16); }
DEV unsigned short f2bf(float x) {
    unsigned u = __float_as_uint(x);
    unsigned r = (u + 0x7fffu + ((u >> 16) & 1u)) >> 16;
    return (unsigned short)r;
}

#define NNEUR 2048
#define DID   128
#define RM    32      // rows (b,n) per block in phase 1

// =====================================================================
// Phase 1: per-(b,n) hypernetwork.  e = slot+region+eid -> LN -> gelu(hW1+b1)
//          -> wb = h1 W2 + b2.  Writes w (bf16, [8192][128]) + bias (f32).
// =====================================================================
__global__ __launch_bounds__(256, 1) void p1_kernel(
    const int* __restrict__ neuron_regions, const int* __restrict__ eids,
    const float* __restrict__ neuron_slot, const float* __restrict__ region_emb,
    const float* __restrict__ eid_emb, const float* __restrict__ ln_gamma,
    const float* __restrict__ ln_beta, const float* __restrict__ W1,
    const float* __restrict__ b1, const float* __restrict__ W2,
    const float* __restrict__ b2, unsigned short* __restrict__ w_ws,
    float* __restrict__ bias_ws)
{
    __shared__ unsigned short hT[128][40];    // h  transposed, bf16  (10.0 KB)
    __shared__ unsigned short h1T[256][40];   // h1 transposed, bf16  (20.0 KB)
    __shared__ float wbuf[4096];              // weight staging tile  (16.0 KB)

    const int tid  = threadIdx.x;
    const int row0 = blockIdx.x * RM;

    // ---------------- Stage A: e + LayerNorm -> hT -------------------
    {
        const int rr = tid >> 3, q = tid & 7;      // 32 rows x 8 threads
        const int row = row0 + rr;
        const int b = row >> 11, n = row & 2047;
        int nr = neuron_regions[b * NNEUR + n];
        nr = min(max(nr, 0), 127);
        int eid = eids[b];
        eid = min(max(eid, 0), 255);
        const float4* ns = (const float4*)(neuron_slot + n * DID + q * 16);
        const float4* re = (const float4*)(region_emb + nr * DID + q * 16);
        const float4* ee = (const float4*)(eid_emb + eid * DID + q * 16);
        float e[16];
#pragma unroll
        for (int i = 0; i < 4; i++) {
            float4 a = ns[i], c = re[i], d = ee[i];
            e[i * 4 + 0] = a.x + c.x + d.x;
            e[i * 4 + 1] = a.y + c.y + d.y;
            e[i * 4 + 2] = a.z + c.z + d.z;
            e[i * 4 + 3] = a.w + c.w + d.w;
        }
        float s = 0.f, s2 = 0.f;
#pragma unroll
        for (int i = 0; i < 16; i++) { s += e[i]; s2 += e[i] * e[i]; }
        s += __shfl_xor(s, 1);  s2 += __shfl_xor(s2, 1);
        s += __shfl_xor(s, 2);  s2 += __shfl_xor(s2, 2);
        s += __shfl_xor(s, 4);  s2 += __shfl_xor(s2, 4);
        const float mu   = s * (1.f / 128.f);
        const float var  = s2 * (1.f / 128.f) - mu * mu;
        const float rstd = rsqrtf(var + 1e-5f);
#pragma unroll
        for (int i = 0; i < 16; i++) {
            const int d = q * 16 + i;
            float h = (e[i] - mu) * rstd * ln_gamma[d] + ln_beta[d];
            hT[d][rr] = f2bf(h);
        }
    }
    __syncthreads();

    // ---------------- Stage B: h1 = gelu(h @ W1 + b1) -> h1T ---------
    {
        const int rg = tid >> 5, cg = tid & 31;   // 8 rowgrp x 4 rows; 32 colgrp x 8 cols
        float acc[4][8];
        {
            float4 bA = *(const float4*)(b1 + cg * 8);
            float4 bB = *(const float4*)(b1 + cg * 8 + 4);
#pragma unroll
            for (int r = 0; r < 4; r++) {
                acc[r][0] = bA.x; acc[r][1] = bA.y; acc[r][2] = bA.z; acc[r][3] = bA.w;
                acc[r][4] = bB.x; acc[r][5] = bB.y; acc[r][6] = bB.z; acc[r][7] = bB.w;
            }
        }
        const int sr = tid >> 4;          // staging row 0..15
        const int sc = (tid & 15) * 16;   // staging col
        float4 stg[4];
        {
            const float4* p = (const float4*)(W1 + sr * 256 + sc);
            stg[0] = p[0]; stg[1] = p[1]; stg[2] = p[2]; stg[3] = p[3];
        }
#pragma unroll 1
        for (int ck = 0; ck < 8; ck++) {    // 8 chunks of 16 k-rows
            float* dst = wbuf + sr * 256 + sc;
            ((float4*)dst)[0] = stg[0]; ((float4*)dst)[1] = stg[1];
            ((float4*)dst)[2] = stg[2]; ((float4*)dst)[3] = stg[3];
            __syncthreads();
            if (ck < 7) {
                const float4* p = (const float4*)(W1 + ((ck + 1) * 16 + sr) * 256 + sc);
                stg[0] = p[0]; stg[1] = p[1]; stg[2] = p[2]; stg[3] = p[3];
            }
#pragma unroll
            for (int kk = 0; kk < 16; kk++) {
                const int k = ck * 16 + kk;
                ushort4 hu = *(const ushort4*)&hT[k][rg * 4];
                float h0 = bf2f(hu.x), h1v = bf2f(hu.y), h2 = bf2f(hu.z), h3 = bf2f(hu.w);
                const float* wr = wbuf + kk * 256 + cg * 8;
                float4 wA = *(const float4*)wr;
                float4 wB = *(const float4*)(wr + 4);
                float wv[8] = {wA.x, wA.y, wA.z, wA.w, wB.x, wB.y, wB.z, wB.w};
#pragma unroll
                for (int j = 0; j < 8; j++) {
                    acc[0][j] += h0 * wv[j];
                    acc[1][j] += h1v * wv[j];
                    acc[2][j] += h2 * wv[j];
                    acc[3][j] += h3 * wv[j];
                }
            }
            __syncthreads();
        }
        // exact gelu + store transposed bf16
#pragma unroll
        for (int r = 0; r < 4; r++) {
#pragma unroll
            for (int j = 0; j < 8; j++) {
                float x = acc[r][j];
                float g = 0.5f * x * (1.f + erff(x * 0.70710678118654752f));
                h1T[cg * 8 + j][rg * 4 + r] = f2bf(g);
            }
        }
    }
    __syncthreads();

    // ---------------- Stage C: wb = h1 @ W2 + b2 ---------------------
    {
        const int rg = tid >> 5, cg = tid & 31;  // 4 rows x 4 cols per thread
        float acc[4][4];
        {
            float4 bb = *(const float4*)(b2 + cg * 4);
#pragma unroll
            for (int r = 0; r < 4; r++) {
                acc[r][0] = bb.x; acc[r][1] = bb.y; acc[r][2] = bb.z; acc[r][3] = bb.w;
            }
        }
        const int sr = tid >> 3;          // staging row 0..31
        const int sc = (tid & 7) * 16;    // 16 cols each
        float stg[16];
#pragma unroll
        for (int j = 0; j < 16; j++) stg[j] = W2[sr * 129 + sc + j];
#pragma unroll 1
        for (int ck = 0; ck < 8; ck++) {    // 8 chunks of 32 k-rows (cols 0..127 only)
            float* dst = wbuf + sr * 128 + sc;
#pragma unroll
            for (int j = 0; j < 4; j++)
                ((float4*)dst)[j] = make_float4(stg[j*4], stg[j*4+1], stg[j*4+2], stg[j*4+3]);
            __syncthreads();
            if (ck < 7) {
                const int kb = ((ck + 1) * 32 + sr) * 129 + sc;
#pragma unroll
                for (int j = 0; j < 16; j++) stg[j] = W2[kb + j];
            }
#pragma unroll
            for (int kk = 0; kk < 32; kk++) {
                const int k = ck * 32 + kk;
                ushort4 hu = *(const ushort4*)&h1T[k][rg * 4];
                float h0 = bf2f(hu.x), h1v = bf2f(hu.y), h2 = bf2f(hu.z), h3 = bf2f(hu.w);
                float4 w = *(const float4*)(wbuf + kk * 128 + cg * 4);
                float wv[4] = {w.x, w.y, w.z, w.w};
#pragma unroll
                for (int j = 0; j < 4; j++) {
                    acc[0][j] += h0 * wv[j];
                    acc[1][j] += h1v * wv[j];
                    acc[2][j] += h2 * wv[j];
                    acc[3][j] += h3 * wv[j];
                }
            }
            __syncthreads();
        }
        // store w as bf16
#pragma unroll
        for (int r = 0; r < 4; r++) {
            const int grow = row0 + rg * 4 + r;
            ushort4 o;
            o.x = f2bf(acc[r][0]); o.y = f2bf(acc[r][1]);
            o.z = f2bf(acc[r][2]); o.w = f2bf(acc[r][3]);
            *(ushort4*)(w_ws + grow * DID + cg * 4) = o;
        }
    }

    // ---------------- bias column (col 128 of W2) --------------------
    {
        const int rr = tid >> 3, q = tid & 7;
        float s = 0.f;
#pragma unroll
        for (int kk = 0; kk < 32; kk++) {
            const int k = q * 32 + kk;
            s += bf2f(h1T[k][rr]) * W2[k * 129 + 128];
        }
        s += __shfl_xor(s, 1);
        s += __shfl_xor(s, 2);
        s += __shfl_xor(s, 4);
        if (q == 0) bias_ws[row0 + rr] = s + b2[128];
    }
}

// =====================================================================
// Phase 2: pred[b,t,n] = dot(U[b,t,lr(b,n),:], w[b,n,:]) + bias[b,n]
// One block per (b,t); U tile staged in LDS (padded stride 132).
// =====================================================================
__global__ __launch_bounds__(256, 1) void p2_kernel(
    const float* __restrict__ U, const int* __restrict__ neuron_regions,
    const int* __restrict__ r_map, const unsigned short* __restrict__ w_ws,
    const float* __restrict__ bias_ws, float* __restrict__ out)
{
    __shared__ float Ut[64][132];
    __shared__ int rmap_s[128];
    const int tid = threadIdx.x;
    const int bid = blockIdx.x;
    const int b = bid >> 7, t = bid & 127;

    {   // stage U[b,t,:,:]  (64 x 128 f32)
        const int r = tid >> 2, c0 = (tid & 3) * 32;
        const float4* src = (const float4*)(U + ((b * 128 + t) * 64 + r) * DID + c0);
#pragma unroll
        for (int j = 0; j < 8; j++) {
            float4 v = src[j];
            *(float4*)&Ut[r][c0 + j * 4] = v;
        }
    }
    if (tid < 128) rmap_s[tid] = r_map[tid];
    __syncthreads();

    const int n_sub = tid >> 2, q = tid & 3;   // 4 lanes per neuron
#pragma unroll 1
    for (int it = 0; it < 32; it++) {
        const int n = it * 64 + n_sub;
        int nr = neuron_regions[b * NNEUR + n];
        nr = min(max(nr, 0), 127);
        const int lr_raw = rmap_s[nr];
        const int lr = min(max(lr_raw, 0), 63);
        const ushort4* wp = (const ushort4*)(w_ws + (b * NNEUR + n) * DID + q * 32);
        const float* up = &Ut[lr][q * 32];
        float acc = 0.f;
#pragma unroll
        for (int g = 0; g < 4; g++) {
            ushort4 wa = wp[g * 2], wbv = wp[g * 2 + 1];
            float4 ua = *(const float4*)(up + g * 8);
            float4 ub = *(const float4*)(up + g * 8 + 4);
            acc += bf2f(wa.x) * ua.x + bf2f(wa.y) * ua.y +
                   bf2f(wa.z) * ua.z + bf2f(wa.w) * ua.w +
                   bf2f(wbv.x) * ub.x + bf2f(wbv.y) * ub.y +
                   bf2f(wbv.z) * ub.z + bf2f(wbv.w) * ub.w;
        }
        acc += __shfl_xor(acc, 1);
        acc += __shfl_xor(acc, 2);
        if (q == 0) {
            float res = (lr_raw < 0) ? 0.f : (acc + bias_ws[b * NNEUR + n]);
            out[(b * 128 + t) * NNEUR + n] = res;
        }
    }
}

extern "C" void kernel_launch(void* const* d_in, const int* in_sizes, int n_in,
                              void* d_out, int out_size, void* d_ws, size_t ws_size,
                              hipStream_t stream)
{
    const float* U              = (const float*)d_in[0];
    const int*   neuron_regions = (const int*)d_in[1];
    const int*   eids           = (const int*)d_in[2];
    const int*   r_map          = (const int*)d_in[3];
    const float* neuron_slot    = (const float*)d_in[4];
    const float* region_emb     = (const float*)d_in[5];
    const float* eid_emb        = (const float*)d_in[6];
    const float* ln_gamma       = (const float*)d_in[7];
    const float* ln_beta        = (const float*)d_in[8];
    const float* W1             = (const float*)d_in[9];
    const float* b1             = (const float*)d_in[10];
    const float* W2             = (const float*)d_in[11];
    const float* b2             = (const float*)d_in[12];

    unsigned short* w_ws = (unsigned short*)d_ws;
    float* bias_ws = (float*)((char*)d_ws + (size_t)8192 * 128 * sizeof(unsigned short));
    float* outp = (float*)d_out;

    hipLaunchKernelGGL(p1_kernel, dim3(256), dim3(256), 0, stream,
                       neuron_regions, eids, neuron_slot, region_emb, eid_emb,
                       ln_gamma, ln_beta, W1, b1, W2, b2, w_ws, bias_ws);
    hipLaunchKernelGGL(p2_kernel, dim3(512), dim3(256), 0, stream,
                       U, neuron_regions, r_map, w_ws, bias_ws, outp);
}

// Round 2
// 41.840 us; speedup vs baseline: 1.9023x; 1.9023x over previous
//
#include <hip/hip_runtime.h>
#include <hip/hip_bf16.h>
#include <math.h>

#define DEV __device__ __forceinline__

typedef __attribute__((ext_vector_type(8))) short short8v;
typedef __attribute__((ext_vector_type(4))) float f32x4;

DEV float bf2f(unsigned short u) { return __uint_as_float(((unsigned)u) << 16); }
DEV unsigned short f2bf(float x) {
    unsigned u = __float_as_uint(x);
    return (unsigned short)((u + 0x7fffu + ((u >> 16) & 1u)) >> 16);
}
DEV unsigned pack2(float lo, float hi) {
    return ((unsigned)f2bf(hi) << 16) | (unsigned)f2bf(lo);
}
DEV f32x4 mfma16(short8v a, short8v b, f32x4 c) {
    return __builtin_amdgcn_mfma_f32_16x16x32_bf16(a, b, c, 0, 0, 0);
}

#define NN 2048

// ==================================================================
// prep: blocks 0..31  W1[128][256] -> W1T bf16 [256][128]
//       blocks 32..63 W2[256][129] cols0..127 -> W2T bf16 [128][256]
//       block  64     w2col[256] = W2[:,128] (f32)
//       blocks 65..68 counting sort of neurons by local region (per b)
// ==================================================================
__global__ __launch_bounds__(256, 1) void prep_kernel(
    const float* __restrict__ W1, const float* __restrict__ W2,
    const int* __restrict__ r_map, const int* __restrict__ neuron_regions,
    unsigned short* __restrict__ W1T, unsigned short* __restrict__ W2T,
    float* __restrict__ w2col, int* __restrict__ order, int* __restrict__ offs)
{
    __shared__ __align__(16) float T[32][33];
    __shared__ int hist[65], starts[66], cursor[65];
    const int tid = threadIdx.x;
    const int bid = blockIdx.x;

    if (bid < 32) {
        const int tr = bid >> 3, tc = bid & 7;
#pragma unroll
        for (int p = 0; p < 4; p++) {
            const int i = p * 8 + (tid >> 5), j = tid & 31;
            T[i][j] = W1[(tr * 32 + i) * 256 + tc * 32 + j];
        }
        __syncthreads();
#pragma unroll
        for (int p = 0; p < 4; p++) {
            const int i = p * 8 + (tid >> 5), j = tid & 31;
            W1T[(tc * 32 + i) * 128 + tr * 32 + j] = f2bf(T[j][i]);
        }
    } else if (bid < 64) {
        const int bb = bid - 32, tr = bb >> 2, tc = bb & 3;
#pragma unroll
        for (int p = 0; p < 4; p++) {
            const int i = p * 8 + (tid >> 5), j = tid & 31;
            T[i][j] = W2[(tr * 32 + i) * 129 + tc * 32 + j];
        }
        __syncthreads();
#pragma unroll
        for (int p = 0; p < 4; p++) {
            const int i = p * 8 + (tid >> 5), j = tid & 31;
            W2T[(tc * 32 + i) * 256 + tr * 32 + j] = f2bf(T[j][i]);
        }
    } else if (bid == 64) {
        w2col[tid] = W2[tid * 129 + 128];
    } else {
        const int b = bid - 65;
        for (int i = tid; i < 65; i += 256) hist[i] = 0;
        __syncthreads();
        for (int n = tid; n < NN; n += 256) {
            int nr = min(max(neuron_regions[b * NN + n], 0), 127);
            int lr = r_map[nr];
            int bin = (lr < 0) ? 64 : min(lr, 63);
            atomicAdd(&hist[bin], 1);
        }
        __syncthreads();
        if (tid == 0) {
            int run = 0;
            for (int i = 0; i < 65; i++) { starts[i] = run; cursor[i] = run; run += hist[i]; }
            starts[65] = run;
        }
        __syncthreads();
        for (int i = tid; i < 66; i += 256) offs[b * 66 + i] = starts[i];
        for (int n = tid; n < NN; n += 256) {
            int nr = min(max(neuron_regions[b * NN + n], 0), 127);
            int lr = r_map[nr];
            int bin = (lr < 0) ? 64 : min(lr, 63);
            int pos = atomicAdd(&cursor[bin], 1);
            order[b * NN + pos] = n;
        }
    }
}

// ==================================================================
// p1: per-(b,n) hypernetwork via bf16 MFMA. 512 blocks x 16 rows.
// ==================================================================
__global__ __launch_bounds__(256, 1) void p1_kernel(
    const int* __restrict__ neuron_regions, const int* __restrict__ eids,
    const float* __restrict__ neuron_slot, const float* __restrict__ region_emb,
    const float* __restrict__ eid_emb, const float* __restrict__ ln_gamma,
    const float* __restrict__ ln_beta, const float* __restrict__ b1,
    const float* __restrict__ b2, const unsigned short* __restrict__ W1T,
    const unsigned short* __restrict__ W2T, const float* __restrict__ w2col,
    unsigned short* __restrict__ w_ws, float* __restrict__ bias_ws)
{
    __shared__ __align__(16) unsigned short hT[16][136];   // h bf16 (also out-bounce)
    __shared__ __align__(16) unsigned short H1[16][264];   // gelu(hW1+b1) bf16
    __shared__ float biasp[16];
    const int tid = threadIdx.x;
    const int row0 = blockIdx.x * 16;
    if (tid < 16) biasp[tid] = 0.f;

    // ---------- Stage A: e + LayerNorm -> hT ----------
    {
        const int rr = tid >> 4, q = tid & 15;    // 16 rows x 16 lanes
        const int row = row0 + rr;
        const int b = row >> 11, n = row & (NN - 1);
        int nr = min(max(neuron_regions[b * NN + n], 0), 127);
        int eid = min(max(eids[b], 0), 255);
        const float* ns = neuron_slot + n * 128 + q * 8;
        const float* re = region_emb + nr * 128 + q * 8;
        const float* ee = eid_emb + eid * 128 + q * 8;
        float e[8];
        {
            float4 a0 = *(const float4*)ns, a1 = *(const float4*)(ns + 4);
            float4 c0 = *(const float4*)re, c1 = *(const float4*)(re + 4);
            float4 d0 = *(const float4*)ee, d1 = *(const float4*)(ee + 4);
            e[0] = a0.x + c0.x + d0.x; e[1] = a0.y + c0.y + d0.y;
            e[2] = a0.z + c0.z + d0.z; e[3] = a0.w + c0.w + d0.w;
            e[4] = a1.x + c1.x + d1.x; e[5] = a1.y + c1.y + d1.y;
            e[6] = a1.z + c1.z + d1.z; e[7] = a1.w + c1.w + d1.w;
        }
        float s = 0.f, s2 = 0.f;
#pragma unroll
        for (int i = 0; i < 8; i++) { s += e[i]; s2 += e[i] * e[i]; }
        s += __shfl_xor(s, 1);  s2 += __shfl_xor(s2, 1);
        s += __shfl_xor(s, 2);  s2 += __shfl_xor(s2, 2);
        s += __shfl_xor(s, 4);  s2 += __shfl_xor(s2, 4);
        s += __shfl_xor(s, 8);  s2 += __shfl_xor(s2, 8);
        const float mu = s * (1.f / 128.f);
        const float var = s2 * (1.f / 128.f) - mu * mu;
        const float rstd = rsqrtf(var + 1e-5f);
        float4 g0 = *(const float4*)(ln_gamma + q * 8), g1 = *(const float4*)(ln_gamma + q * 8 + 4);
        float4 t0 = *(const float4*)(ln_beta + q * 8),  t1 = *(const float4*)(ln_beta + q * 8 + 4);
        float gm[8] = {g0.x, g0.y, g0.z, g0.w, g1.x, g1.y, g1.z, g1.w};
        float bt[8] = {t0.x, t0.y, t0.z, t0.w, t1.x, t1.y, t1.z, t1.w};
        float h[8];
#pragma unroll
        for (int i = 0; i < 8; i++) h[i] = (e[i] - mu) * rstd * gm[i] + bt[i];
        uint4 pk;
        pk.x = pack2(h[0], h[1]); pk.y = pack2(h[2], h[3]);
        pk.z = pack2(h[4], h[5]); pk.w = pack2(h[6], h[7]);
        *(uint4*)&hT[rr][q * 8] = pk;
    }
    __syncthreads();

    const int wv = tid >> 6, l = tid & 63;
    const int lr = l & 15, lh = l >> 4;

    // ---------- GEMM1: C1[16x256] = h @ W1  (wave wv owns cols wv*64..+63) ----------
    short8v afr[4];
#pragma unroll
    for (int ks = 0; ks < 4; ks++)
        afr[ks] = *(const short8v*)&hT[lr][ks * 32 + lh * 8];

    f32x4 acc1[4];
    short8v bfr[4][4];
    float w2c[4];
#pragma unroll
    for (int nt = 0; nt < 4; nt++) {
        const int n = wv * 64 + nt * 16 + lr;
#pragma unroll
        for (int ks = 0; ks < 4; ks++)
            bfr[nt][ks] = *(const short8v*)(W1T + n * 128 + ks * 32 + lh * 8);
        const float bb = b1[n];
        acc1[nt].x = bb; acc1[nt].y = bb; acc1[nt].z = bb; acc1[nt].w = bb;
        w2c[nt] = w2col[n];
    }
#pragma unroll
    for (int nt = 0; nt < 4; nt++)
#pragma unroll
        for (int ks = 0; ks < 4; ks++)
            acc1[nt] = mfma16(afr[ks], bfr[nt][ks], acc1[nt]);

    // ---------- GELU -> H1 (bf16) + bias-column partials ----------
    float pb[4] = {0.f, 0.f, 0.f, 0.f};
#pragma unroll
    for (int nt = 0; nt < 4; nt++) {
        const int n = wv * 64 + nt * 16 + lr;
#pragma unroll
        for (int j = 0; j < 4; j++) {
            const float x = acc1[nt][j];
            const float g = 0.5f * x * (1.f + erff(x * 0.70710678118654752f));
            H1[lh * 4 + j][n] = f2bf(g);
            pb[j] += g * w2c[nt];
        }
    }
#pragma unroll
    for (int j = 0; j < 4; j++) {
        pb[j] += __shfl_xor(pb[j], 1);
        pb[j] += __shfl_xor(pb[j], 2);
        pb[j] += __shfl_xor(pb[j], 4);
        pb[j] += __shfl_xor(pb[j], 8);
    }
    if (lr == 0) {
#pragma unroll
        for (int j = 0; j < 4; j++) atomicAdd(&biasp[lh * 4 + j], pb[j]);
    }
    __syncthreads();

    if (tid < 16) bias_ws[row0 + tid] = biasp[tid] + b2[128];

    // ---------- GEMM2: C2[16x128] = H1 @ W2  (wave wv owns cols wv*32..+31) ----------
    short8v a2[8];
#pragma unroll
    for (int ks = 0; ks < 8; ks++)
        a2[ks] = *(const short8v*)&H1[lr][ks * 32 + lh * 8];

    f32x4 acc2[2];
    short8v b2f[2][8];
#pragma unroll
    for (int nt = 0; nt < 2; nt++) {
        const int n = wv * 32 + nt * 16 + lr;
#pragma unroll
        for (int ks = 0; ks < 8; ks++)
            b2f[nt][ks] = *(const short8v*)(W2T + n * 256 + ks * 32 + lh * 8);
        const float bb = b2[n];
        acc2[nt].x = bb; acc2[nt].y = bb; acc2[nt].z = bb; acc2[nt].w = bb;
    }
#pragma unroll
    for (int nt = 0; nt < 2; nt++)
#pragma unroll
        for (int ks = 0; ks < 8; ks++)
            acc2[nt] = mfma16(a2[ks], b2f[nt][ks], acc2[nt]);

    // ---------- bounce C2 through LDS (reuse hT), coalesced store ----------
#pragma unroll
    for (int nt = 0; nt < 2; nt++) {
        const int n = wv * 32 + nt * 16 + lr;
#pragma unroll
        for (int j = 0; j < 4; j++)
            hT[lh * 4 + j][n] = f2bf(acc2[nt][j]);
    }
    __syncthreads();
    {
        const int r = tid >> 4, c = tid & 15;
        uint4 v = *(const uint4*)&hT[r][c * 8];
        *(uint4*)(w_ws + (row0 + r) * 128 + c * 8) = v;
    }
}

// ==================================================================
// p2: blocks 0..255 = (b, region-slot) gather-GEMM; 256..259 dead-zero.
// ==================================================================
__global__ __launch_bounds__(256, 1) void p2_kernel(
    const float* __restrict__ U, const int* __restrict__ order,
    const int* __restrict__ offs, const unsigned short* __restrict__ w_ws,
    const float* __restrict__ bias_ws, float* __restrict__ out)
{
    __shared__ __align__(16) unsigned short Ubf[128][136];
    __shared__ __align__(16) unsigned short Bt[32][136];
    __shared__ int nidS[32];
    __shared__ float biasS[32];
    const int tid = threadIdx.x;
    const int bid = blockIdx.x;

    if (bid >= 256) {   // dead neurons -> zeros (no-op when none)
        const int b = bid - 256;
        const int s64 = offs[b * 66 + 64], s65 = offs[b * 66 + 65];
        const int cnt = s65 - s64;
        for (int idx = tid; idx < cnt * 128; idx += 256) {
            const int j = idx >> 7, t = idx & 127;
            const int n = order[b * NN + s64 + j];
            out[(b * 128 + t) * NN + n] = 0.f;
        }
        return;
    }

    const int b = bid >> 6, slot = bid & 63;
    const int s0 = offs[b * 66 + slot], s1 = offs[b * 66 + slot + 1];
    const int cnt = s1 - s0;
    if (cnt <= 0) return;

    // stage U[b, :, slot, :] as bf16
    {
        const int t = tid >> 1, half = tid & 1;
        const float* src = U + ((size_t)((b * 128 + t) * 64 + slot)) * 128 + half * 64;
        unsigned short* dst = &Ubf[t][half * 64];
#pragma unroll
        for (int j = 0; j < 16; j++) {
            float4 v = ((const float4*)src)[j];
            ((uint2*)dst)[j] = make_uint2(pack2(v.x, v.y), pack2(v.z, v.w));
        }
    }
    __syncthreads();

    const int wv = tid >> 6, l = tid & 63;
    const int lr = l & 15, lh = l >> 4;

    short8v afr[2][4];
#pragma unroll
    for (int mt = 0; mt < 2; mt++)
#pragma unroll
        for (int ks = 0; ks < 4; ks++)
            afr[mt][ks] = *(const short8v*)&Ubf[wv * 32 + mt * 16 + lr][ks * 32 + lh * 8];

    const int nChunks = (cnt + 31) >> 5;
    for (int c = 0; c < nChunks; c++) {
        const int base = s0 + c * 32;
        const int cc = min(cnt - c * 32, 32);
        __syncthreads();   // previous chunk's Bt/nidS reads complete
        if (tid < 32) {
            const int nid = (tid < cc) ? order[b * NN + base + tid] : -1;
            nidS[tid] = nid;
            biasS[tid] = (nid >= 0) ? bias_ws[b * NN + nid] : 0.f;
        }
        {
            const int jj = tid >> 3, q = tid & 7;
            const int nid = (jj < cc) ? order[b * NN + base + jj] : -1;
            unsigned short* dst = &Bt[jj][q * 16];
            if (nid >= 0) {
                const uint4* src = (const uint4*)(w_ws + ((size_t)(b * NN + nid)) * 128 + q * 16);
                ((uint4*)dst)[0] = src[0];
                ((uint4*)dst)[1] = src[1];
            } else {
                ((uint4*)dst)[0] = make_uint4(0, 0, 0, 0);
                ((uint4*)dst)[1] = make_uint4(0, 0, 0, 0);
            }
        }
        __syncthreads();

        f32x4 acc[2][2];
#pragma unroll
        for (int mt = 0; mt < 2; mt++)
#pragma unroll
            for (int nt = 0; nt < 2; nt++) {
                acc[mt][nt].x = 0.f; acc[mt][nt].y = 0.f;
                acc[mt][nt].z = 0.f; acc[mt][nt].w = 0.f;
            }
        short8v bfr[2][4];
#pragma unroll
        for (int nt = 0; nt < 2; nt++)
#pragma unroll
            for (int ks = 0; ks < 4; ks++)
                bfr[nt][ks] = *(const short8v*)&Bt[nt * 16 + lr][ks * 32 + lh * 8];
#pragma unroll
        for (int mt = 0; mt < 2; mt++)
#pragma unroll
            for (int nt = 0; nt < 2; nt++)
#pragma unroll
                for (int ks = 0; ks < 4; ks++)
                    acc[mt][nt] = mfma16(afr[mt][ks], bfr[nt][ks], acc[mt][nt]);

#pragma unroll
        for (int nt = 0; nt < 2; nt++) {
            const int j = nt * 16 + lr;
            const int nid = nidS[j];
            if (nid >= 0) {
                const float bs = biasS[j];
#pragma unroll
                for (int mt = 0; mt < 2; mt++) {
                    const int tt = wv * 32 + mt * 16 + lh * 4;
#pragma unroll
                    for (int jr = 0; jr < 4; jr++)
                        out[(b * 128 + tt + jr) * NN + nid] = acc[mt][nt][jr] + bs;
                }
            }
        }
    }
}

extern "C" void kernel_launch(void* const* d_in, const int* in_sizes, int n_in,
                              void* d_out, int out_size, void* d_ws, size_t ws_size,
                              hipStream_t stream)
{
    const float* U              = (const float*)d_in[0];
    const int*   neuron_regions = (const int*)d_in[1];
    const int*   eids           = (const int*)d_in[2];
    const int*   r_map          = (const int*)d_in[3];
    const float* neuron_slot    = (const float*)d_in[4];
    const float* region_emb     = (const float*)d_in[5];
    const float* eid_emb        = (const float*)d_in[6];
    const float* ln_gamma       = (const float*)d_in[7];
    const float* ln_beta        = (const float*)d_in[8];
    const float* W1             = (const float*)d_in[9];
    const float* b1             = (const float*)d_in[10];
    const float* W2             = (const float*)d_in[11];
    const float* b2             = (const float*)d_in[12];

    char* ws = (char*)d_ws;
    unsigned short* w_ws  = (unsigned short*)(ws);                    // 2 MB
    float*          bias_ws = (float*)(ws + 2097152);                 // 32 KB
    unsigned short* W1T   = (unsigned short*)(ws + 2129920);          // 64 KB
    unsigned short* W2T   = (unsigned short*)(ws + 2195456);          // 64 KB
    float*          w2col = (float*)(ws + 2260992);                   // 1 KB
    int*            order = (int*)(ws + 2262016);                     // 32 KB
    int*            offs  = (int*)(ws + 2294784);                     // ~1 KB
    float* outp = (float*)d_out;

    hipLaunchKernelGGL(prep_kernel, dim3(69), dim3(256), 0, stream,
                       W1, W2, r_map, neuron_regions, W1T, W2T, w2col, order, offs);
    hipLaunchKernelGGL(p1_kernel, dim3(512), dim3(256), 0, stream,
                       neuron_regions, eids, neuron_slot, region_emb, eid_emb,
                       ln_gamma, ln_beta, b1, b2, W1T, W2T, w2col, w_ws, bias_ws);
    hipLaunchKernelGGL(p2_kernel, dim3(260), dim3(256), 0, stream,
                       U, order, offs, w_ws, bias_ws, outp);
}